// Round 15
// baseline (134842.383 us; speedup 1.0000x reference)
//
#include <hip/hip_runtime.h>
#include <cstddef>

#define NSTEP 4096
#define PIN4(v) asm volatile("" : "+v"((v).x), "+v"((v).y), "+v"((v).z), "+v"((v).w))
#define FMA4(W,V,A) { (A)=fmaf((W).x,(V).x,(A)); (A)=fmaf((W).y,(V).y,(A)); (A)=fmaf((W).z,(V).z,(A)); (A)=fmaf((W).w,(V).w,(A)); }

// Cross-XCD coherent scalar load/store through the LLC (no fences, no L2 inv).
__device__ __forceinline__ float ldc(const float* p) {
  return __hip_atomic_load(p, __ATOMIC_RELAXED, __HIP_MEMORY_SCOPE_AGENT);
}
__device__ __forceinline__ void stc(float* p, float v) {
  __hip_atomic_store(p, v, __ATOMIC_RELAXED, __HIP_MEMORY_SCOPE_AGENT);
}
__device__ __forceinline__ unsigned ldu(const unsigned* p) {
  return __hip_atomic_load(p, __ATOMIC_RELAXED, __HIP_MEMORY_SCOPE_AGENT);
}

// ===================== BatchNorm over timestep channels =====================
__global__ __launch_bounds__(256) void bn_kernel(const float* __restrict__ x,
                                                 const float* __restrict__ bn_w,
                                                 const float* __restrict__ bn_b,
                                                 float* __restrict__ xn)
{
  const int t   = blockIdx.x;        // 0..1023
  const int tid = threadIdx.x;       // 256 = B*F
  const int b   = tid >> 6;
  const int f   = tid & 63;
  const float v = x[((size_t)b * 1024 + t) * 64 + f];
  float s = v, ss = v * v;
  #pragma unroll
  for (int off = 32; off > 0; off >>= 1) {
    s  += __shfl_down(s, off);
    ss += __shfl_down(ss, off);
  }
  __shared__ float sh[8];
  const int w = tid >> 6;
  if ((tid & 63) == 0) { sh[w] = s; sh[4 + w] = ss; }
  __syncthreads();
  const float S    = sh[0] + sh[1] + sh[2] + sh[3];
  const float SS   = sh[4] + sh[5] + sh[6] + sh[7];
  const float mean = S * (1.0f / 256.0f);
  const float var  = SS * (1.0f / 256.0f) - mean * mean;  // biased, matches jnp.var
  const float inv  = rsqrtf(var + 1e-5f);
  const float scale = bn_w[t] * inv;
  const float shift = bn_b[t] - mean * scale;
  xn[((size_t)b * 1024 + t) * 64 + f] = v * scale + shift;
}

// ========== per-LAYER barrier (fence-free, cumulative) ======================
// ROUND-14 DEADLOCK LESSON: group slots use indices 16 + 16*g, g up to 15 ->
// max index 256. Regions were only 256 u32 apart, so L1's group 15 aliased
// L2's ROOT counter -> exact-match last-block test misfired -> root never
// advanced -> global hang. Regions are now 512 u32 each (no collision).
template<int NBLK, int GROUPS>
__device__ __forceinline__ void layer_barrier(unsigned* __restrict__ bar,
                                              unsigned step1, int tid, int lb)
{
  constexpr unsigned GSZ = NBLK / GROUPS;
  static_assert(NBLK % GROUPS == 0, "grouping");
  static_assert(16 + 16 * (GROUPS - 1) < 512, "group slot fits region");
  __syncthreads();
  if (tid == 0) {
    unsigned* gcnt = bar + 16 + 16 * (lb / (int)GSZ);
    const unsigned a = __hip_atomic_fetch_add(gcnt, 1u, __ATOMIC_RELAXED,
                                              __HIP_MEMORY_SCOPE_AGENT);
    if (a == step1 * GSZ - 1u)
      __hip_atomic_fetch_add(bar, 1u, __ATOMIC_RELAXED, __HIP_MEMORY_SCOPE_AGENT);
    const unsigned tgt = step1 * (unsigned)GROUPS;
    while (ldu(bar) < tgt) __builtin_amdgcn_s_sleep(1);
    asm volatile("" ::: "memory");
  }
  __syncthreads();
}

// Wait until the upstream layer's root reaches `need` (its step done+visible).
__device__ __forceinline__ void wait_upstream(const unsigned* __restrict__ uproot,
                                              unsigned need, int tid)
{
  if (tid == 0) {
    while (ldu(uproot) < need) __builtin_amdgcn_s_sleep(1);
    asm volatile("" ::: "memory");
  }
  __syncthreads();
}

// ===================== wave helpers =========================================
__device__ __forceinline__ void reduce4(float& a0, float& a1, float& a2, float& a3)
{
  #pragma unroll
  for (int off = 32; off; off >>= 1) {
    a0 += __shfl_xor(a0, off);
    a1 += __shfl_xor(a1, off);
    a2 += __shfl_xor(a2, off);
    a3 += __shfl_xor(a3, off);
  }
}

__device__ __forceinline__ float lstm_act4(float a0, float a1, float a2, float a3,
                                           float4 bs, float& c)
{
  const float ig = 1.0f / (1.0f + expf(-(a0 + bs.x)));
  const float fg = 1.0f / (1.0f + expf(-(a1 + bs.y)));
  const float og = 1.0f / (1.0f + expf(-(a3 + bs.w)));
  const float gt = tanhf(a2 + bs.z);
  c = fg * c + ig * gt;
  return og * tanhf(c);
}

// ===================== ONE persistent kernel: ELASTIC layer pipeline ========
// Each layer runs its OWN 4096-step loop, synced by (a) its per-layer barrier
// (own recurrence) and (b) the upstream layer's root counter (dataflow:
// root_{l-1} >= GROUPS*(t+1) <=> h_{l-1}(t) is at the LLC). Layers overlap;
// total ~= slowest layer's loop. Deadlock-tolerant: L1 depends only on L1,
// so even without co-residency the pipeline drains sequentially.
//
// Occupancy pinned both sides: waves_per_eu(4,4). min=4 -> VGPR cap 128 ->
// 2 blocks/CU -> 480 blocks co-resident. max=4 -> forbids the 8-waves/EU RA
// target that spilled to VGPR=64 and pushed 200 GB scratch to HBM (round 13).
#define L1J(j)  { const float4 v = *(const float4*)&hbuf[(j)*256 + lane*4]; \
  FMA4(h0##j, v, a0); FMA4(h1##j, v, a1); FMA4(h2##j, v, a2); FMA4(h3##j, v, a3); }
#define L2XJ(j) { const float4 v = *(const float4*)&hbuf[(j)*256+lane*4]; \
  FMA4(i0##j,v,a0); FMA4(i1##j,v,a1); FMA4(i2##j,v,a2); FMA4(i3##j,v,a3); }
#define L2HJ(j) { const float4 v = *(const float4*)&hbuf[2048 + (j)*256+lane*4]; \
  FMA4(m0##j,v,a0); FMA4(m1##j,v,a1); FMA4(m2##j,v,a2); FMA4(m3##j,v,a3); }
#define L3XJ(j) { const float4 v = *(const float4*)&hbuf[(j)*256+lane*4]; \
  FMA4(d0##j,v,a0); FMA4(d1##j,v,a1); FMA4(d2##j,v,a2); FMA4(d3##j,v,a3); }
#define L4XJ(j) { const float4 v = *(const float4*)&hbuf[(j)*256+lane*4]; \
  FMA4(f0##j,v,a0); FMA4(f1##j,v,a1); FMA4(f2##j,v,a2); FMA4(f3##j,v,a3); }

__global__ __launch_bounds__(512)
__attribute__((amdgpu_waves_per_eu(4, 4)))
void lstm_all(const float* __restrict__ win1, const float* __restrict__ whh1,
              const float* __restrict__ bih1, const float* __restrict__ bhh1,
              const float* __restrict__ win2, const float* __restrict__ whh2,
              const float* __restrict__ bih2, const float* __restrict__ bhh2,
              const float* __restrict__ win3, const float* __restrict__ whh3,
              const float* __restrict__ bih3, const float* __restrict__ bhh3,
              const float* __restrict__ win4, const float* __restrict__ whh4,
              const float* __restrict__ bih4, const float* __restrict__ bhh4,
              const float* __restrict__ X,    // (4096,64) bn output (prior kernel)
              float* __restrict__ H1t,        // (4097,2048), row r = h1(r-1)
              float* __restrict__ H2t, float* __restrict__ H3t,
              float* __restrict__ H4t, float* __restrict__ out,
              unsigned* __restrict__ bar)     // 4 regions of 512 u32: L1..L4
{
  __shared__ __align__(16) float hbuf[3072];  // worst case: L2 x(2048)+h(1024)
  const int tid = threadIdx.x, lane = tid & 63, wsl = tid >> 6;
  const int blk = blockIdx.x;                 // 0..479
  unsigned* bar1 = bar;
  unsigned* bar2 = bar + 512;
  unsigned* bar3 = bar + 1024;
  unsigned* bar4 = bar + 1536;

  if (blk < 256) {                            // ========= L1: IN=64 H=2048
    constexpr int H = 2048;
    const int lb = blk;
    const int hid = lb * 8 + wsl;             // 2048 waves == H
    const size_t r0 = hid, r1 = H + hid, r2 = 2 * H + hid, r3 = 3 * H + hid;
    float4 wi = make_float4(win1[r0 * 64 + lane], win1[r1 * 64 + lane],
                            win1[r2 * 64 + lane], win1[r3 * 64 + lane]);
    PIN4(wi);
    const float4* p0 = (const float4*)(whh1 + r0 * H);
    const float4* p1 = (const float4*)(whh1 + r1 * H);
    const float4* p2 = (const float4*)(whh1 + r2 * H);
    const float4* p3 = (const float4*)(whh1 + r3 * H);
    float4 h00=p0[0*64+lane], h01=p0[1*64+lane], h02=p0[2*64+lane], h03=p0[3*64+lane],
           h04=p0[4*64+lane], h05=p0[5*64+lane], h06=p0[6*64+lane], h07=p0[7*64+lane];
    float4 h10=p1[0*64+lane], h11=p1[1*64+lane], h12=p1[2*64+lane], h13=p1[3*64+lane],
           h14=p1[4*64+lane], h15=p1[5*64+lane], h16=p1[6*64+lane], h17=p1[7*64+lane];
    float4 h20=p2[0*64+lane], h21=p2[1*64+lane], h22=p2[2*64+lane], h23=p2[3*64+lane],
           h24=p2[4*64+lane], h25=p2[5*64+lane], h26=p2[6*64+lane], h27=p2[7*64+lane];
    float4 h30=p3[0*64+lane], h31=p3[1*64+lane], h32=p3[2*64+lane], h33=p3[3*64+lane],
           h34=p3[4*64+lane], h35=p3[5*64+lane], h36=p3[6*64+lane], h37=p3[7*64+lane];
    PIN4(h00); PIN4(h01); PIN4(h02); PIN4(h03); PIN4(h04); PIN4(h05); PIN4(h06); PIN4(h07);
    PIN4(h10); PIN4(h11); PIN4(h12); PIN4(h13); PIN4(h14); PIN4(h15); PIN4(h16); PIN4(h17);
    PIN4(h20); PIN4(h21); PIN4(h22); PIN4(h23); PIN4(h24); PIN4(h25); PIN4(h26); PIN4(h27);
    PIN4(h30); PIN4(h31); PIN4(h32); PIN4(h33); PIN4(h34); PIN4(h35); PIN4(h36); PIN4(h37);
    float4 bs = make_float4(bih1[r0] + bhh1[r0], bih1[r1] + bhh1[r1],
                            bih1[r2] + bhh1[r2], bih1[r3] + bhh1[r3]);
    PIN4(bs);
    float c = 0.0f;
    #pragma unroll 1
    for (int t = 0; t < NSTEP; ++t) {
      {
        const float* hrow = H1t + (size_t)t * H;
        #pragma unroll
        for (int k = 0; k < 4; ++k) hbuf[tid + 512 * k] = ldc(hrow + tid + 512 * k);
      }
      __syncthreads();
      const float xv = X[(size_t)t * 64 + lane];   // prior-kernel data: plain
      float a0 = wi.x * xv, a1 = wi.y * xv, a2 = wi.z * xv, a3 = wi.w * xv;
      L1J(0) L1J(1) L1J(2) L1J(3) L1J(4) L1J(5) L1J(6) L1J(7)
      reduce4(a0, a1, a2, a3);
      const float hn = lstm_act4(a0, a1, a2, a3, bs, c);
      if (lane == 0) stc(&H1t[(size_t)(t + 1) * H + hid], hn);
      asm volatile("s_waitcnt vmcnt(0)" ::: "memory");   // h at LLC before count
      layer_barrier<256, 16>(bar1, (unsigned)(t + 1), tid, lb);
    }
  } else if (blk < 384) {                     // ========= L2: IN=2048 H=1024
    const int lb = blk - 256;                 // 0..127
    const int hid = lb * 8 + wsl;             // 0..1023
    const float* X2 = H1t + 2048;             // row t = h1(t) (in-flight)
    const size_t R0 = hid, R1 = 1024 + hid, R2 = 2048 + hid, R3 = 3072 + hid;
    const float4* pi0 = (const float4*)(win2 + R0 * 2048);
    const float4* pi1 = (const float4*)(win2 + R1 * 2048);
    const float4* pi2 = (const float4*)(win2 + R2 * 2048);
    const float4* pi3 = (const float4*)(win2 + R3 * 2048);
    const float4* ph0 = (const float4*)(whh2 + R0 * 1024);
    const float4* ph1 = (const float4*)(whh2 + R1 * 1024);
    const float4* ph2 = (const float4*)(whh2 + R2 * 1024);
    const float4* ph3 = (const float4*)(whh2 + R3 * 1024);
    float4 i00=pi0[0*64+lane], i01=pi0[1*64+lane], i02=pi0[2*64+lane], i03=pi0[3*64+lane],
           i04=pi0[4*64+lane], i05=pi0[5*64+lane], i06=pi0[6*64+lane], i07=pi0[7*64+lane];
    float4 i10=pi1[0*64+lane], i11=pi1[1*64+lane], i12=pi1[2*64+lane], i13=pi1[3*64+lane],
           i14=pi1[4*64+lane], i15=pi1[5*64+lane], i16=pi1[6*64+lane], i17=pi1[7*64+lane];
    float4 i20=pi2[0*64+lane], i21=pi2[1*64+lane], i22=pi2[2*64+lane], i23=pi2[3*64+lane],
           i24=pi2[4*64+lane], i25=pi2[5*64+lane], i26=pi2[6*64+lane], i27=pi2[7*64+lane];
    float4 i30=pi3[0*64+lane], i31=pi3[1*64+lane], i32=pi3[2*64+lane], i33=pi3[3*64+lane],
           i34=pi3[4*64+lane], i35=pi3[5*64+lane], i36=pi3[6*64+lane], i37=pi3[7*64+lane];
    float4 m00=ph0[0*64+lane], m01=ph0[1*64+lane], m02=ph0[2*64+lane], m03=ph0[3*64+lane];
    float4 m10=ph1[0*64+lane], m11=ph1[1*64+lane], m12=ph1[2*64+lane], m13=ph1[3*64+lane];
    float4 m20=ph2[0*64+lane], m21=ph2[1*64+lane], m22=ph2[2*64+lane], m23=ph2[3*64+lane];
    float4 m30=ph3[0*64+lane], m31=ph3[1*64+lane], m32=ph3[2*64+lane], m33=ph3[3*64+lane];
    PIN4(i00); PIN4(i01); PIN4(i02); PIN4(i03); PIN4(i04); PIN4(i05); PIN4(i06); PIN4(i07);
    PIN4(i10); PIN4(i11); PIN4(i12); PIN4(i13); PIN4(i14); PIN4(i15); PIN4(i16); PIN4(i17);
    PIN4(i20); PIN4(i21); PIN4(i22); PIN4(i23); PIN4(i24); PIN4(i25); PIN4(i26); PIN4(i27);
    PIN4(i30); PIN4(i31); PIN4(i32); PIN4(i33); PIN4(i34); PIN4(i35); PIN4(i36); PIN4(i37);
    PIN4(m00); PIN4(m01); PIN4(m02); PIN4(m03);
    PIN4(m10); PIN4(m11); PIN4(m12); PIN4(m13);
    PIN4(m20); PIN4(m21); PIN4(m22); PIN4(m23);
    PIN4(m30); PIN4(m31); PIN4(m32); PIN4(m33);
    float4 bs = make_float4(bih2[R0] + bhh2[R0], bih2[R1] + bhh2[R1],
                            bih2[R2] + bhh2[R2], bih2[R3] + bhh2[R3]);
    PIN4(bs);
    float c = 0.0f;
    #pragma unroll 1
    for (int t = 0; t < NSTEP; ++t) {
      wait_upstream(bar1, 16u * (unsigned)(t + 1), tid);   // h1(t) at LLC
      {
        const float* xrow = X2  + (size_t)t * 2048;
        const float* hrow = H2t + (size_t)t * 1024;
        #pragma unroll
        for (int k = 0; k < 4; ++k) hbuf[tid + 512 * k] = ldc(xrow + tid + 512 * k);
        #pragma unroll
        for (int k = 0; k < 2; ++k) hbuf[2048 + tid + 512 * k] = ldc(hrow + tid + 512 * k);
      }
      __syncthreads();
      float a0 = 0.f, a1 = 0.f, a2 = 0.f, a3 = 0.f;
      L2XJ(0) L2XJ(1) L2XJ(2) L2XJ(3) L2XJ(4) L2XJ(5) L2XJ(6) L2XJ(7)
      L2HJ(0) L2HJ(1) L2HJ(2) L2HJ(3)
      reduce4(a0, a1, a2, a3);
      const float hn = lstm_act4(a0, a1, a2, a3, bs, c);
      if (lane == 0) stc(&H2t[(size_t)(t + 1) * 1024 + hid], hn);
      asm volatile("s_waitcnt vmcnt(0)" ::: "memory");
      layer_barrier<128, 16>(bar2, (unsigned)(t + 1), tid, lb);
    }
  } else if (blk < 448) {                     // ========= L3: IN=1024 H=512
    const int lb = blk - 384;                 // 0..63
    const int hid = lb * 8 + wsl;             // 0..511
    const float* X3 = H2t + 1024;             // row t = h2(t)
    const size_t R0 = hid, R1 = 512 + hid, R2 = 1024 + hid, R3 = 1536 + hid;
    const float4* pi0 = (const float4*)(win3 + R0 * 1024);
    const float4* pi1 = (const float4*)(win3 + R1 * 1024);
    const float4* pi2 = (const float4*)(win3 + R2 * 1024);
    const float4* pi3 = (const float4*)(win3 + R3 * 1024);
    const float4* ph0 = (const float4*)(whh3 + R0 * 512);
    const float4* ph1 = (const float4*)(whh3 + R1 * 512);
    const float4* ph2 = (const float4*)(whh3 + R2 * 512);
    const float4* ph3 = (const float4*)(whh3 + R3 * 512);
    float4 d00=pi0[0*64+lane], d01=pi0[1*64+lane], d02=pi0[2*64+lane], d03=pi0[3*64+lane];
    float4 d10=pi1[0*64+lane], d11=pi1[1*64+lane], d12=pi1[2*64+lane], d13=pi1[3*64+lane];
    float4 d20=pi2[0*64+lane], d21=pi2[1*64+lane], d22=pi2[2*64+lane], d23=pi2[3*64+lane];
    float4 d30=pi3[0*64+lane], d31=pi3[1*64+lane], d32=pi3[2*64+lane], d33=pi3[3*64+lane];
    float4 e00=ph0[0*64+lane], e01=ph0[1*64+lane];
    float4 e10=ph1[0*64+lane], e11=ph1[1*64+lane];
    float4 e20=ph2[0*64+lane], e21=ph2[1*64+lane];
    float4 e30=ph3[0*64+lane], e31=ph3[1*64+lane];
    PIN4(d00); PIN4(d01); PIN4(d02); PIN4(d03);
    PIN4(d10); PIN4(d11); PIN4(d12); PIN4(d13);
    PIN4(d20); PIN4(d21); PIN4(d22); PIN4(d23);
    PIN4(d30); PIN4(d31); PIN4(d32); PIN4(d33);
    PIN4(e00); PIN4(e01); PIN4(e10); PIN4(e11);
    PIN4(e20); PIN4(e21); PIN4(e30); PIN4(e31);
    float4 bs = make_float4(bih3[R0] + bhh3[R0], bih3[R1] + bhh3[R1],
                            bih3[R2] + bhh3[R2], bih3[R3] + bhh3[R3]);
    PIN4(bs);
    float c = 0.0f;
    #pragma unroll 1
    for (int t = 0; t < NSTEP; ++t) {
      wait_upstream(bar2, 16u * (unsigned)(t + 1), tid);   // h2(t) at LLC
      {
        const float* xrow = X3  + (size_t)t * 1024;
        const float* hrow = H3t + (size_t)t * 512;
        #pragma unroll
        for (int k = 0; k < 2; ++k) hbuf[tid + 512 * k] = ldc(xrow + tid + 512 * k);
        hbuf[1024 + tid] = ldc(hrow + tid);
      }
      __syncthreads();
      float a0 = 0.f, a1 = 0.f, a2 = 0.f, a3 = 0.f;
      L3XJ(0) L3XJ(1) L3XJ(2) L3XJ(3)
      {
        const float4 v = *(const float4*)&hbuf[1024 + 0*256 + lane*4];
        FMA4(e00,v,a0); FMA4(e10,v,a1); FMA4(e20,v,a2); FMA4(e30,v,a3);
      }
      {
        const float4 v = *(const float4*)&hbuf[1024 + 1*256 + lane*4];
        FMA4(e01,v,a0); FMA4(e11,v,a1); FMA4(e21,v,a2); FMA4(e31,v,a3);
      }
      reduce4(a0, a1, a2, a3);
      const float hn = lstm_act4(a0, a1, a2, a3, bs, c);
      if (lane == 0) stc(&H3t[(size_t)(t + 1) * 512 + hid], hn);
      asm volatile("s_waitcnt vmcnt(0)" ::: "memory");
      layer_barrier<64, 8>(bar3, (unsigned)(t + 1), tid, lb);
    }
  } else {                                    // ========= L4: IN=512 H=256
    const int lb = blk - 448;                 // 0..31
    const int hid = lb * 8 + wsl;             // 0..255
    const float* X4 = H3t + 512;              // row t = h3(t)
    const size_t R0 = hid, R1 = 256 + hid, R2 = 512 + hid, R3 = 768 + hid;
    const float4* pi0 = (const float4*)(win4 + R0 * 512);
    const float4* pi1 = (const float4*)(win4 + R1 * 512);
    const float4* pi2 = (const float4*)(win4 + R2 * 512);
    const float4* pi3 = (const float4*)(win4 + R3 * 512);
    const float4* ph0 = (const float4*)(whh4 + R0 * 256);
    const float4* ph1 = (const float4*)(whh4 + R1 * 256);
    const float4* ph2 = (const float4*)(whh4 + R2 * 256);
    const float4* ph3 = (const float4*)(whh4 + R3 * 256);
    float4 f00=pi0[0*64+lane], f01=pi0[1*64+lane];
    float4 f10=pi1[0*64+lane], f11=pi1[1*64+lane];
    float4 f20=pi2[0*64+lane], f21=pi2[1*64+lane];
    float4 f30=pi3[0*64+lane], f31=pi3[1*64+lane];
    float4 g0=ph0[lane], g1=ph1[lane], g2=ph2[lane], g3=ph3[lane];
    PIN4(f00); PIN4(f01); PIN4(f10); PIN4(f11);
    PIN4(f20); PIN4(f21); PIN4(f30); PIN4(f31);
    PIN4(g0); PIN4(g1); PIN4(g2); PIN4(g3);
    float4 bs = make_float4(bih4[R0] + bhh4[R0], bih4[R1] + bhh4[R1],
                            bih4[R2] + bhh4[R2], bih4[R3] + bhh4[R3]);
    PIN4(bs);
    float c = 0.0f;
    #pragma unroll 1
    for (int t = 0; t < NSTEP; ++t) {
      wait_upstream(bar3, 8u * (unsigned)(t + 1), tid);    // h3(t) at LLC
      {
        const float* xrow = X4  + (size_t)t * 512;
        const float* hrow = H4t + (size_t)t * 256;
        hbuf[tid] = ldc(xrow + tid);
        if (tid < 256) hbuf[512 + tid] = ldc(hrow + tid);
      }
      __syncthreads();
      float a0 = 0.f, a1 = 0.f, a2 = 0.f, a3 = 0.f;
      L4XJ(0) L4XJ(1)
      {
        const float4 v = *(const float4*)&hbuf[512 + lane*4];
        FMA4(g0,v,a0); FMA4(g1,v,a1); FMA4(g2,v,a2); FMA4(g3,v,a3);
      }
      reduce4(a0, a1, a2, a3);
      const float hn = lstm_act4(a0, a1, a2, a3, bs, c);
      if (lane == 0) {
        stc(&H4t[(size_t)(t + 1) * 256 + hid], hn);
        out[(size_t)t * 256 + hid] = hn;          // host-read: plain
      }
      asm volatile("s_waitcnt vmcnt(0)" ::: "memory");
      layer_barrier<32, 8>(bar4, (unsigned)(t + 1), tid, lb);
    }
  }
}

// ===================== Fallback: round-1 streaming path =====================
struct Params {
  const float* xn;
  const float* w_ih[4];
  const float* w_hh[4];
  const float* b_ih[4];
  const float* b_hh[4];
  float* h[4];
  float* c[4];
  float* out;
  int s;
};

__global__ __launch_bounds__(256) void step_kernel(Params p)
{
  const int lane = threadIdx.x & 63;
  const int W = blockIdx.x * 4 + (threadIdx.x >> 6);

  int layer, h, H, IN, t;
  if (W < 2048)      { layer = 0; h = W;        H = 2048; IN = 64;   t = p.s;     }
  else if (W < 3072) { layer = 1; h = W - 2048; H = 1024; IN = 2048; t = p.s - 1; }
  else if (W < 3584) { layer = 2; h = W - 3072; H = 512;  IN = 1024; t = p.s - 2; }
  else               { layer = 3; h = W - 3584; H = 256;  IN = 512;  t = p.s - 3; }
  if (t < 0 || t >= NSTEP) return;

  const float* xin;
  if (layer == 0) xin = p.xn + (size_t)t * 64;
  else            xin = p.h[layer - 1] + (size_t)(t & 1) * IN;
  const float* hprev = p.h[layer] + (size_t)((t + 1) & 1) * H;
  float*       hout  = p.h[layer] + (size_t)(t & 1) * H;
  const float* wih = p.w_ih[layer];
  const float* whh = p.w_hh[layer];

  float acc[4];
  #pragma unroll
  for (int g = 0; g < 4; ++g) {
    const size_t r = (size_t)g * H + h;
    const float* wi = wih + r * IN;
    const float* wh = whh + r * (size_t)H;
    float a = 0.0f;
    for (int k = lane; k < IN; k += 64) a += wi[k] * xin[k];
    for (int k = lane; k < H;  k += 64) a += wh[k] * hprev[k];
    acc[g] = a;
  }
  #pragma unroll
  for (int off = 32; off > 0; off >>= 1) {
    #pragma unroll
    for (int g = 0; g < 4; ++g) acc[g] += __shfl_down(acc[g], off);
  }
  if (lane == 0) {
    const float* bi = p.b_ih[layer];
    const float* bh = p.b_hh[layer];
    const float gi = acc[0] + bi[h]         + bh[h];
    const float gf = acc[1] + bi[H + h]     + bh[H + h];
    const float gg = acc[2] + bi[2 * H + h] + bh[2 * H + h];
    const float go = acc[3] + bi[3 * H + h] + bh[3 * H + h];
    const float ig = 1.0f / (1.0f + expf(-gi));
    const float fg = 1.0f / (1.0f + expf(-gf));
    const float og = 1.0f / (1.0f + expf(-go));
    const float gt = tanhf(gg);
    const float cn = fg * p.c[layer][h] + ig * gt;
    const float hn = og * tanhf(cn);
    p.c[layer][h] = cn;
    hout[h] = hn;
    if (layer == 3) p.out[(size_t)t * 256 + h] = hn;
  }
}

// ===================== host launch ==========================================
extern "C" void kernel_launch(void* const* d_in, const int* in_sizes, int n_in,
                              void* d_out, int out_size, void* d_ws, size_t ws_size,
                              hipStream_t stream)
{
  const float* x    = (const float*)d_in[0];
  const float* bn_w = (const float*)d_in[1];
  const float* bn_b = (const float*)d_in[2];
  const float* wih[4]; const float* whh[4]; const float* bih[4]; const float* bhh[4];
  for (int l = 0; l < 4; ++l) {
    wih[l] = (const float*)d_in[3 + 4 * l];
    whh[l] = (const float*)d_in[4 + 4 * l];
    bih[l] = (const float*)d_in[5 + 4 * l];
    bhh[l] = (const float*)d_in[6 + 4 * l];
  }
  float* out = (float*)d_out;

  const size_t XN  = (size_t)NSTEP * 64;
  const size_t NH1 = (size_t)(NSTEP + 1) * 2048;
  const size_t NH2 = (size_t)(NSTEP + 1) * 1024;
  const size_t NH3 = (size_t)(NSTEP + 1) * 512;
  const size_t NH4 = (size_t)(NSTEP + 1) * 256;
  const size_t BARB = 8192;   // 4 x 512 u32 barrier regions
  const size_t need = BARB + (XN + NH1 + NH2 + NH3 + NH4) * sizeof(float);

  if (ws_size >= need) {
    unsigned* bar = (unsigned*)d_ws;          // 4 x 512 u32 regions (L1..L4)
    float* fb = (float*)((char*)d_ws + BARB);
    float* xn = fb;
    float* H1 = xn + XN;
    float* H2 = H1 + NH1;
    float* H3 = H2 + NH2;
    float* H4 = H3 + NH3;

    hipMemsetAsync(bar, 0, BARB, stream);
    hipMemsetAsync(H1, 0, 2048 * sizeof(float), stream);
    hipMemsetAsync(H2, 0, 1024 * sizeof(float), stream);
    hipMemsetAsync(H3, 0,  512 * sizeof(float), stream);
    hipMemsetAsync(H4, 0,  256 * sizeof(float), stream);

    bn_kernel<<<1024, 256, 0, stream>>>(x, bn_w, bn_b, xn);

    lstm_all<<<480, 512, 0, stream>>>(wih[0], whh[0], bih[0], bhh[0],
                                      wih[1], whh[1], bih[1], bhh[1],
                                      wih[2], whh[2], bih[2], bhh[2],
                                      wih[3], whh[3], bih[3], bhh[3],
                                      xn, H1, H2, H3, H4, out, bar);
    return;
  }

  // -------- fallback: streaming pipeline (proven) --------
  Params p;
  for (int l = 0; l < 4; ++l) { p.w_ih[l] = wih[l]; p.w_hh[l] = whh[l];
                                p.b_ih[l] = bih[l]; p.b_hh[l] = bhh[l]; }
  float* ws = (float*)d_ws;
  float* xn = ws;
  float* st = ws + (size_t)NSTEP * 64;
  p.xn = xn;
  const int Hs[4] = {2048, 1024, 512, 256};
  float* cur = st;
  for (int l = 0; l < 4; ++l) { p.h[l] = cur; cur += 2 * Hs[l]; }
  for (int l = 0; l < 4; ++l) { p.c[l] = cur; cur += Hs[l]; }
  p.out = out;

  const size_t state_bytes = (size_t)(cur - st) * sizeof(float);
  hipMemsetAsync(st, 0, state_bytes, stream);
  bn_kernel<<<1024, 256, 0, stream>>>(x, bn_w, bn_b, xn);
  for (int s = 0; s < NSTEP + 3; ++s) {
    p.s = s;
    step_kernel<<<960, 256, 0, stream>>>(p);
  }
}

// Round 16
// 47902.643 us; speedup vs baseline: 2.8149x; 2.8149x over previous
//
#include <hip/hip_runtime.h>
#include <cstddef>

#define NSTEP 4096
#define PIN4(v) asm volatile("" : "+v"((v).x), "+v"((v).y), "+v"((v).z), "+v"((v).w))
#define FMA4(W,V,A) { (A)=fmaf((W).x,(V).x,(A)); (A)=fmaf((W).y,(V).y,(A)); (A)=fmaf((W).z,(V).z,(A)); (A)=fmaf((W).w,(V).w,(A)); }

// Cross-XCD coherent scalar load/store through the LLC (no fences, no L2 inv).
__device__ __forceinline__ float ldc(const float* p) {
  return __hip_atomic_load(p, __ATOMIC_RELAXED, __HIP_MEMORY_SCOPE_AGENT);
}
__device__ __forceinline__ void stc(float* p, float v) {
  __hip_atomic_store(p, v, __ATOMIC_RELAXED, __HIP_MEMORY_SCOPE_AGENT);
}
__device__ __forceinline__ unsigned ldu(const unsigned* p) {
  return __hip_atomic_load(p, __ATOMIC_RELAXED, __HIP_MEMORY_SCOPE_AGENT);
}

// ===================== BatchNorm over timestep channels =====================
__global__ __launch_bounds__(256) void bn_kernel(const float* __restrict__ x,
                                                 const float* __restrict__ bn_w,
                                                 const float* __restrict__ bn_b,
                                                 float* __restrict__ xn)
{
  const int t   = blockIdx.x;        // 0..1023
  const int tid = threadIdx.x;       // 256 = B*F
  const int b   = tid >> 6;
  const int f   = tid & 63;
  const float v = x[((size_t)b * 1024 + t) * 64 + f];
  float s = v, ss = v * v;
  #pragma unroll
  for (int off = 32; off > 0; off >>= 1) {
    s  += __shfl_down(s, off);
    ss += __shfl_down(ss, off);
  }
  __shared__ float sh[8];
  const int w = tid >> 6;
  if ((tid & 63) == 0) { sh[w] = s; sh[4 + w] = ss; }
  __syncthreads();
  const float S    = sh[0] + sh[1] + sh[2] + sh[3];
  const float SS   = sh[4] + sh[5] + sh[6] + sh[7];
  const float mean = S * (1.0f / 256.0f);
  const float var  = SS * (1.0f / 256.0f) - mean * mean;  // biased, matches jnp.var
  const float inv  = rsqrtf(var + 1e-5f);
  const float scale = bn_w[t] * inv;
  const float shift = bn_b[t] - mean * scale;
  xn[((size_t)b * 1024 + t) * 64 + f] = v * scale + shift;
}

// ========== per-LAYER barrier (fence-free, cumulative, 512-u32 regions) =====
template<int NBLK, int GROUPS>
__device__ __forceinline__ void layer_barrier(unsigned* __restrict__ bar,
                                              unsigned step1, int tid, int lb)
{
  constexpr unsigned GSZ = NBLK / GROUPS;
  static_assert(NBLK % GROUPS == 0, "grouping");
  static_assert(16 + 16 * (GROUPS - 1) < 512, "group slot fits region");
  __syncthreads();
  if (tid == 0) {
    unsigned* gcnt = bar + 16 + 16 * (lb / (int)GSZ);
    const unsigned a = __hip_atomic_fetch_add(gcnt, 1u, __ATOMIC_RELAXED,
                                              __HIP_MEMORY_SCOPE_AGENT);
    if (a == step1 * GSZ - 1u)
      __hip_atomic_fetch_add(bar, 1u, __ATOMIC_RELAXED, __HIP_MEMORY_SCOPE_AGENT);
    const unsigned tgt = step1 * (unsigned)GROUPS;
    while (ldu(bar) < tgt) __builtin_amdgcn_s_sleep(1);
    asm volatile("" ::: "memory");
  }
  __syncthreads();
}

// Wait until the upstream layer's root reaches `need` (its step done+visible).
__device__ __forceinline__ void wait_upstream(const unsigned* __restrict__ uproot,
                                              unsigned need, int tid)
{
  if (tid == 0) {
    while (ldu(uproot) < need) __builtin_amdgcn_s_sleep(1);
    asm volatile("" ::: "memory");
  }
  __syncthreads();
}

// ===================== wave helpers =========================================
__device__ __forceinline__ void reduce4(float& a0, float& a1, float& a2, float& a3)
{
  #pragma unroll
  for (int off = 32; off; off >>= 1) {
    a0 += __shfl_xor(a0, off);
    a1 += __shfl_xor(a1, off);
    a2 += __shfl_xor(a2, off);
    a3 += __shfl_xor(a3, off);
  }
}

__device__ __forceinline__ float lstm_act4(float a0, float a1, float a2, float a3,
                                           float4 bs, float& c)
{
  const float ig = 1.0f / (1.0f + expf(-(a0 + bs.x)));
  const float fg = 1.0f / (1.0f + expf(-(a1 + bs.y)));
  const float og = 1.0f / (1.0f + expf(-(a3 + bs.w)));
  const float gt = tanhf(a2 + bs.z);
  c = fg * c + ig * gt;
  return og * tanhf(c);
}

// ===================== ONE persistent kernel: ELASTIC layer pipeline ========
// Each layer runs its OWN 4096-step loop, synced by (a) its per-layer barrier
// (own recurrence) and (b) the upstream layer's root counter (dataflow).
// Deadlock-tolerant: each layer's barrier only needs ITS OWN blocks resident
// (256/128/64/32 <= 256 CUs even at 1 block/CU) -> worst case layers drain
// sequentially; best case (2 blocks/CU) they overlap fully.
//
// OCCUPANCY-ATTRIBUTE A/B (round 13/15 vs 9/10/11):
//   waves_per_eu(4,4) / launch_bounds(512,4)  -> RA picked 64 VGPR -> ~150
//   floats/lane spilled to scratch -> 200+ GB HBM/dispatch -> 130+ ms.
//   waves_per_eu(2,2) / launch_bounds(512,1)  -> RA picked 112 VGPR (3x) ->
//   cheap-spill regime, and 112 <= 128 still physically allows 2 blocks/CU
//   (hardware occupancy follows ACTUAL VGPRs, not the attribute).
// This round: (2,2) on the elastic kernel.
#define L1J(j)  { const float4 v = *(const float4*)&hbuf[(j)*256 + lane*4]; \
  FMA4(h0##j, v, a0); FMA4(h1##j, v, a1); FMA4(h2##j, v, a2); FMA4(h3##j, v, a3); }
#define L2XJ(j) { const float4 v = *(const float4*)&hbuf[(j)*256+lane*4]; \
  FMA4(i0##j,v,a0); FMA4(i1##j,v,a1); FMA4(i2##j,v,a2); FMA4(i3##j,v,a3); }
#define L2HJ(j) { const float4 v = *(const float4*)&hbuf[2048 + (j)*256+lane*4]; \
  FMA4(m0##j,v,a0); FMA4(m1##j,v,a1); FMA4(m2##j,v,a2); FMA4(m3##j,v,a3); }
#define L3XJ(j) { const float4 v = *(const float4*)&hbuf[(j)*256+lane*4]; \
  FMA4(d0##j,v,a0); FMA4(d1##j,v,a1); FMA4(d2##j,v,a2); FMA4(d3##j,v,a3); }
#define L4XJ(j) { const float4 v = *(const float4*)&hbuf[(j)*256+lane*4]; \
  FMA4(f0##j,v,a0); FMA4(f1##j,v,a1); FMA4(f2##j,v,a2); FMA4(f3##j,v,a3); }

__global__ __launch_bounds__(512)
__attribute__((amdgpu_waves_per_eu(2, 2)))
void lstm_all(const float* __restrict__ win1, const float* __restrict__ whh1,
              const float* __restrict__ bih1, const float* __restrict__ bhh1,
              const float* __restrict__ win2, const float* __restrict__ whh2,
              const float* __restrict__ bih2, const float* __restrict__ bhh2,
              const float* __restrict__ win3, const float* __restrict__ whh3,
              const float* __restrict__ bih3, const float* __restrict__ bhh3,
              const float* __restrict__ win4, const float* __restrict__ whh4,
              const float* __restrict__ bih4, const float* __restrict__ bhh4,
              const float* __restrict__ X,    // (4096,64) bn output (prior kernel)
              float* __restrict__ H1t,        // (4097,2048), row r = h1(r-1)
              float* __restrict__ H2t, float* __restrict__ H3t,
              float* __restrict__ H4t, float* __restrict__ out,
              unsigned* __restrict__ bar)     // 4 regions of 512 u32: L1..L4
{
  __shared__ __align__(16) float hbuf[3072];  // worst case: L2 x(2048)+h(1024)
  const int tid = threadIdx.x, lane = tid & 63, wsl = tid >> 6;
  const int blk = blockIdx.x;                 // 0..479
  unsigned* bar1 = bar;
  unsigned* bar2 = bar + 512;
  unsigned* bar3 = bar + 1024;
  unsigned* bar4 = bar + 1536;

  if (blk < 256) {                            // ========= L1: IN=64 H=2048
    constexpr int H = 2048;
    const int lb = blk;
    const int hid = lb * 8 + wsl;             // 2048 waves == H
    const size_t r0 = hid, r1 = H + hid, r2 = 2 * H + hid, r3 = 3 * H + hid;
    float4 wi = make_float4(win1[r0 * 64 + lane], win1[r1 * 64 + lane],
                            win1[r2 * 64 + lane], win1[r3 * 64 + lane]);
    PIN4(wi);
    const float4* p0 = (const float4*)(whh1 + r0 * H);
    const float4* p1 = (const float4*)(whh1 + r1 * H);
    const float4* p2 = (const float4*)(whh1 + r2 * H);
    const float4* p3 = (const float4*)(whh1 + r3 * H);
    float4 h00=p0[0*64+lane], h01=p0[1*64+lane], h02=p0[2*64+lane], h03=p0[3*64+lane],
           h04=p0[4*64+lane], h05=p0[5*64+lane], h06=p0[6*64+lane], h07=p0[7*64+lane];
    float4 h10=p1[0*64+lane], h11=p1[1*64+lane], h12=p1[2*64+lane], h13=p1[3*64+lane],
           h14=p1[4*64+lane], h15=p1[5*64+lane], h16=p1[6*64+lane], h17=p1[7*64+lane];
    float4 h20=p2[0*64+lane], h21=p2[1*64+lane], h22=p2[2*64+lane], h23=p2[3*64+lane],
           h24=p2[4*64+lane], h25=p2[5*64+lane], h26=p2[6*64+lane], h27=p2[7*64+lane];
    float4 h30=p3[0*64+lane], h31=p3[1*64+lane], h32=p3[2*64+lane], h33=p3[3*64+lane],
           h34=p3[4*64+lane], h35=p3[5*64+lane], h36=p3[6*64+lane], h37=p3[7*64+lane];
    PIN4(h00); PIN4(h01); PIN4(h02); PIN4(h03); PIN4(h04); PIN4(h05); PIN4(h06); PIN4(h07);
    PIN4(h10); PIN4(h11); PIN4(h12); PIN4(h13); PIN4(h14); PIN4(h15); PIN4(h16); PIN4(h17);
    PIN4(h20); PIN4(h21); PIN4(h22); PIN4(h23); PIN4(h24); PIN4(h25); PIN4(h26); PIN4(h27);
    PIN4(h30); PIN4(h31); PIN4(h32); PIN4(h33); PIN4(h34); PIN4(h35); PIN4(h36); PIN4(h37);
    float4 bs = make_float4(bih1[r0] + bhh1[r0], bih1[r1] + bhh1[r1],
                            bih1[r2] + bhh1[r2], bih1[r3] + bhh1[r3]);
    PIN4(bs);
    float c = 0.0f;
    #pragma unroll 1
    for (int t = 0; t < NSTEP; ++t) {
      {
        const float* hrow = H1t + (size_t)t * H;
        #pragma unroll
        for (int k = 0; k < 4; ++k) hbuf[tid + 512 * k] = ldc(hrow + tid + 512 * k);
      }
      __syncthreads();
      const float xv = X[(size_t)t * 64 + lane];   // prior-kernel data: plain
      float a0 = wi.x * xv, a1 = wi.y * xv, a2 = wi.z * xv, a3 = wi.w * xv;
      L1J(0) L1J(1) L1J(2) L1J(3) L1J(4) L1J(5) L1J(6) L1J(7)
      reduce4(a0, a1, a2, a3);
      const float hn = lstm_act4(a0, a1, a2, a3, bs, c);
      if (lane == 0) stc(&H1t[(size_t)(t + 1) * H + hid], hn);
      asm volatile("s_waitcnt vmcnt(0)" ::: "memory");   // h at LLC before count
      layer_barrier<256, 16>(bar1, (unsigned)(t + 1), tid, lb);
    }
  } else if (blk < 384) {                     // ========= L2: IN=2048 H=1024
    const int lb = blk - 256;                 // 0..127
    const int hid = lb * 8 + wsl;             // 0..1023
    const float* X2 = H1t + 2048;             // row t = h1(t) (in-flight)
    const size_t R0 = hid, R1 = 1024 + hid, R2 = 2048 + hid, R3 = 3072 + hid;
    const float4* pi0 = (const float4*)(win2 + R0 * 2048);
    const float4* pi1 = (const float4*)(win2 + R1 * 2048);
    const float4* pi2 = (const float4*)(win2 + R2 * 2048);
    const float4* pi3 = (const float4*)(win2 + R3 * 2048);
    const float4* ph0 = (const float4*)(whh2 + R0 * 1024);
    const float4* ph1 = (const float4*)(whh2 + R1 * 1024);
    const float4* ph2 = (const float4*)(whh2 + R2 * 1024);
    const float4* ph3 = (const float4*)(whh2 + R3 * 1024);
    float4 i00=pi0[0*64+lane], i01=pi0[1*64+lane], i02=pi0[2*64+lane], i03=pi0[3*64+lane],
           i04=pi0[4*64+lane], i05=pi0[5*64+lane], i06=pi0[6*64+lane], i07=pi0[7*64+lane];
    float4 i10=pi1[0*64+lane], i11=pi1[1*64+lane], i12=pi1[2*64+lane], i13=pi1[3*64+lane],
           i14=pi1[4*64+lane], i15=pi1[5*64+lane], i16=pi1[6*64+lane], i17=pi1[7*64+lane];
    float4 i20=pi2[0*64+lane], i21=pi2[1*64+lane], i22=pi2[2*64+lane], i23=pi2[3*64+lane],
           i24=pi2[4*64+lane], i25=pi2[5*64+lane], i26=pi2[6*64+lane], i27=pi2[7*64+lane];
    float4 i30=pi3[0*64+lane], i31=pi3[1*64+lane], i32=pi3[2*64+lane], i33=pi3[3*64+lane],
           i34=pi3[4*64+lane], i35=pi3[5*64+lane], i36=pi3[6*64+lane], i37=pi3[7*64+lane];
    float4 m00=ph0[0*64+lane], m01=ph0[1*64+lane], m02=ph0[2*64+lane], m03=ph0[3*64+lane];
    float4 m10=ph1[0*64+lane], m11=ph1[1*64+lane], m12=ph1[2*64+lane], m13=ph1[3*64+lane];
    float4 m20=ph2[0*64+lane], m21=ph2[1*64+lane], m22=ph2[2*64+lane], m23=ph2[3*64+lane];
    float4 m30=ph3[0*64+lane], m31=ph3[1*64+lane], m32=ph3[2*64+lane], m33=ph3[3*64+lane];
    PIN4(i00); PIN4(i01); PIN4(i02); PIN4(i03); PIN4(i04); PIN4(i05); PIN4(i06); PIN4(i07);
    PIN4(i10); PIN4(i11); PIN4(i12); PIN4(i13); PIN4(i14); PIN4(i15); PIN4(i16); PIN4(i17);
    PIN4(i20); PIN4(i21); PIN4(i22); PIN4(i23); PIN4(i24); PIN4(i25); PIN4(i26); PIN4(i27);
    PIN4(i30); PIN4(i31); PIN4(i32); PIN4(i33); PIN4(i34); PIN4(i35); PIN4(i36); PIN4(i37);
    PIN4(m00); PIN4(m01); PIN4(m02); PIN4(m03);
    PIN4(m10); PIN4(m11); PIN4(m12); PIN4(m13);
    PIN4(m20); PIN4(m21); PIN4(m22); PIN4(m23);
    PIN4(m30); PIN4(m31); PIN4(m32); PIN4(m33);
    float4 bs = make_float4(bih2[R0] + bhh2[R0], bih2[R1] + bhh2[R1],
                            bih2[R2] + bhh2[R2], bih2[R3] + bhh2[R3]);
    PIN4(bs);
    float c = 0.0f;
    #pragma unroll 1
    for (int t = 0; t < NSTEP; ++t) {
      wait_upstream(bar1, 16u * (unsigned)(t + 1), tid);   // h1(t) at LLC
      {
        const float* xrow = X2  + (size_t)t * 2048;
        const float* hrow = H2t + (size_t)t * 1024;
        #pragma unroll
        for (int k = 0; k < 4; ++k) hbuf[tid + 512 * k] = ldc(xrow + tid + 512 * k);
        #pragma unroll
        for (int k = 0; k < 2; ++k) hbuf[2048 + tid + 512 * k] = ldc(hrow + tid + 512 * k);
      }
      __syncthreads();
      float a0 = 0.f, a1 = 0.f, a2 = 0.f, a3 = 0.f;
      L2XJ(0) L2XJ(1) L2XJ(2) L2XJ(3) L2XJ(4) L2XJ(5) L2XJ(6) L2XJ(7)
      L2HJ(0) L2HJ(1) L2HJ(2) L2HJ(3)
      reduce4(a0, a1, a2, a3);
      const float hn = lstm_act4(a0, a1, a2, a3, bs, c);
      if (lane == 0) stc(&H2t[(size_t)(t + 1) * 1024 + hid], hn);
      asm volatile("s_waitcnt vmcnt(0)" ::: "memory");
      layer_barrier<128, 16>(bar2, (unsigned)(t + 1), tid, lb);
    }
  } else if (blk < 448) {                     // ========= L3: IN=1024 H=512
    const int lb = blk - 384;                 // 0..63
    const int hid = lb * 8 + wsl;             // 0..511
    const float* X3 = H2t + 1024;             // row t = h2(t)
    const size_t R0 = hid, R1 = 512 + hid, R2 = 1024 + hid, R3 = 1536 + hid;
    const float4* pi0 = (const float4*)(win3 + R0 * 1024);
    const float4* pi1 = (const float4*)(win3 + R1 * 1024);
    const float4* pi2 = (const float4*)(win3 + R2 * 1024);
    const float4* pi3 = (const float4*)(win3 + R3 * 1024);
    const float4* ph0 = (const float4*)(whh3 + R0 * 512);
    const float4* ph1 = (const float4*)(whh3 + R1 * 512);
    const float4* ph2 = (const float4*)(whh3 + R2 * 512);
    const float4* ph3 = (const float4*)(whh3 + R3 * 512);
    float4 d00=pi0[0*64+lane], d01=pi0[1*64+lane], d02=pi0[2*64+lane], d03=pi0[3*64+lane];
    float4 d10=pi1[0*64+lane], d11=pi1[1*64+lane], d12=pi1[2*64+lane], d13=pi1[3*64+lane];
    float4 d20=pi2[0*64+lane], d21=pi2[1*64+lane], d22=pi2[2*64+lane], d23=pi2[3*64+lane];
    float4 d30=pi3[0*64+lane], d31=pi3[1*64+lane], d32=pi3[2*64+lane], d33=pi3[3*64+lane];
    float4 e00=ph0[0*64+lane], e01=ph0[1*64+lane];
    float4 e10=ph1[0*64+lane], e11=ph1[1*64+lane];
    float4 e20=ph2[0*64+lane], e21=ph2[1*64+lane];
    float4 e30=ph3[0*64+lane], e31=ph3[1*64+lane];
    PIN4(d00); PIN4(d01); PIN4(d02); PIN4(d03);
    PIN4(d10); PIN4(d11); PIN4(d12); PIN4(d13);
    PIN4(d20); PIN4(d21); PIN4(d22); PIN4(d23);
    PIN4(d30); PIN4(d31); PIN4(d32); PIN4(d33);
    PIN4(e00); PIN4(e01); PIN4(e10); PIN4(e11);
    PIN4(e20); PIN4(e21); PIN4(e30); PIN4(e31);
    float4 bs = make_float4(bih3[R0] + bhh3[R0], bih3[R1] + bhh3[R1],
                            bih3[R2] + bhh3[R2], bih3[R3] + bhh3[R3]);
    PIN4(bs);
    float c = 0.0f;
    #pragma unroll 1
    for (int t = 0; t < NSTEP; ++t) {
      wait_upstream(bar2, 16u * (unsigned)(t + 1), tid);   // h2(t) at LLC
      {
        const float* xrow = X3  + (size_t)t * 1024;
        const float* hrow = H3t + (size_t)t * 512;
        #pragma unroll
        for (int k = 0; k < 2; ++k) hbuf[tid + 512 * k] = ldc(xrow + tid + 512 * k);
        hbuf[1024 + tid] = ldc(hrow + tid);
      }
      __syncthreads();
      float a0 = 0.f, a1 = 0.f, a2 = 0.f, a3 = 0.f;
      L3XJ(0) L3XJ(1) L3XJ(2) L3XJ(3)
      {
        const float4 v = *(const float4*)&hbuf[1024 + 0*256 + lane*4];
        FMA4(e00,v,a0); FMA4(e10,v,a1); FMA4(e20,v,a2); FMA4(e30,v,a3);
      }
      {
        const float4 v = *(const float4*)&hbuf[1024 + 1*256 + lane*4];
        FMA4(e01,v,a0); FMA4(e11,v,a1); FMA4(e21,v,a2); FMA4(e31,v,a3);
      }
      reduce4(a0, a1, a2, a3);
      const float hn = lstm_act4(a0, a1, a2, a3, bs, c);
      if (lane == 0) stc(&H3t[(size_t)(t + 1) * 512 + hid], hn);
      asm volatile("s_waitcnt vmcnt(0)" ::: "memory");
      layer_barrier<64, 8>(bar3, (unsigned)(t + 1), tid, lb);
    }
  } else {                                    // ========= L4: IN=512 H=256
    const int lb = blk - 448;                 // 0..31
    const int hid = lb * 8 + wsl;             // 0..255
    const float* X4 = H3t + 512;              // row t = h3(t)
    const size_t R0 = hid, R1 = 256 + hid, R2 = 512 + hid, R3 = 768 + hid;
    const float4* pi0 = (const float4*)(win4 + R0 * 512);
    const float4* pi1 = (const float4*)(win4 + R1 * 512);
    const float4* pi2 = (const float4*)(win4 + R2 * 512);
    const float4* pi3 = (const float4*)(win4 + R3 * 512);
    const float4* ph0 = (const float4*)(whh4 + R0 * 256);
    const float4* ph1 = (const float4*)(whh4 + R1 * 256);
    const float4* ph2 = (const float4*)(whh4 + R2 * 256);
    const float4* ph3 = (const float4*)(whh4 + R3 * 256);
    float4 f00=pi0[0*64+lane], f01=pi0[1*64+lane];
    float4 f10=pi1[0*64+lane], f11=pi1[1*64+lane];
    float4 f20=pi2[0*64+lane], f21=pi2[1*64+lane];
    float4 f30=pi3[0*64+lane], f31=pi3[1*64+lane];
    float4 g0=ph0[lane], g1=ph1[lane], g2=ph2[lane], g3=ph3[lane];
    PIN4(f00); PIN4(f01); PIN4(f10); PIN4(f11);
    PIN4(f20); PIN4(f21); PIN4(f30); PIN4(f31);
    PIN4(g0); PIN4(g1); PIN4(g2); PIN4(g3);
    float4 bs = make_float4(bih4[R0] + bhh4[R0], bih4[R1] + bhh4[R1],
                            bih4[R2] + bhh4[R2], bih4[R3] + bhh4[R3]);
    PIN4(bs);
    float c = 0.0f;
    #pragma unroll 1
    for (int t = 0; t < NSTEP; ++t) {
      wait_upstream(bar3, 8u * (unsigned)(t + 1), tid);    // h3(t) at LLC
      {
        const float* xrow = X4  + (size_t)t * 512;
        const float* hrow = H4t + (size_t)t * 256;
        hbuf[tid] = ldc(xrow + tid);
        if (tid < 256) hbuf[512 + tid] = ldc(hrow + tid);
      }
      __syncthreads();
      float a0 = 0.f, a1 = 0.f, a2 = 0.f, a3 = 0.f;
      L4XJ(0) L4XJ(1)
      {
        const float4 v = *(const float4*)&hbuf[512 + lane*4];
        FMA4(g0,v,a0); FMA4(g1,v,a1); FMA4(g2,v,a2); FMA4(g3,v,a3);
      }
      reduce4(a0, a1, a2, a3);
      const float hn = lstm_act4(a0, a1, a2, a3, bs, c);
      if (lane == 0) {
        stc(&H4t[(size_t)(t + 1) * 256 + hid], hn);
        out[(size_t)t * 256 + hid] = hn;          // host-read: plain
      }
      asm volatile("s_waitcnt vmcnt(0)" ::: "memory");
      layer_barrier<32, 8>(bar4, (unsigned)(t + 1), tid, lb);
    }
  }
}

// ===================== Fallback: round-1 streaming path =====================
struct Params {
  const float* xn;
  const float* w_ih[4];
  const float* w_hh[4];
  const float* b_ih[4];
  const float* b_hh[4];
  float* h[4];
  float* c[4];
  float* out;
  int s;
};

__global__ __launch_bounds__(256) void step_kernel(Params p)
{
  const int lane = threadIdx.x & 63;
  const int W = blockIdx.x * 4 + (threadIdx.x >> 6);

  int layer, h, H, IN, t;
  if (W < 2048)      { layer = 0; h = W;        H = 2048; IN = 64;   t = p.s;     }
  else if (W < 3072) { layer = 1; h = W - 2048; H = 1024; IN = 2048; t = p.s - 1; }
  else if (W < 3584) { layer = 2; h = W - 3072; H = 512;  IN = 1024; t = p.s - 2; }
  else               { layer = 3; h = W - 3584; H = 256;  IN = 512;  t = p.s - 3; }
  if (t < 0 || t >= NSTEP) return;

  const float* xin;
  if (layer == 0) xin = p.xn + (size_t)t * 64;
  else            xin = p.h[layer - 1] + (size_t)(t & 1) * IN;
  const float* hprev = p.h[layer] + (size_t)((t + 1) & 1) * H;
  float*       hout  = p.h[layer] + (size_t)(t & 1) * H;
  const float* wih = p.w_ih[layer];
  const float* whh = p.w_hh[layer];

  float acc[4];
  #pragma unroll
  for (int g = 0; g < 4; ++g) {
    const size_t r = (size_t)g * H + h;
    const float* wi = wih + r * IN;
    const float* wh = whh + r * (size_t)H;
    float a = 0.0f;
    for (int k = lane; k < IN; k += 64) a += wi[k] * xin[k];
    for (int k = lane; k < H;  k += 64) a += wh[k] * hprev[k];
    acc[g] = a;
  }
  #pragma unroll
  for (int off = 32; off > 0; off >>= 1) {
    #pragma unroll
    for (int g = 0; g < 4; ++g) acc[g] += __shfl_down(acc[g], off);
  }
  if (lane == 0) {
    const float* bi = p.b_ih[layer];
    const float* bh = p.b_hh[layer];
    const float gi = acc[0] + bi[h]         + bh[h];
    const float gf = acc[1] + bi[H + h]     + bh[H + h];
    const float gg = acc[2] + bi[2 * H + h] + bh[2 * H + h];
    const float go = acc[3] + bi[3 * H + h] + bh[3 * H + h];
    const float ig = 1.0f / (1.0f + expf(-gi));
    const float fg = 1.0f / (1.0f + expf(-gf));
    const float og = 1.0f / (1.0f + expf(-go));
    const float gt = tanhf(gg);
    const float cn = fg * p.c[layer][h] + ig * gt;
    const float hn = og * tanhf(cn);
    p.c[layer][h] = cn;
    hout[h] = hn;
    if (layer == 3) p.out[(size_t)t * 256 + h] = hn;
  }
}

// ===================== host launch ==========================================
extern "C" void kernel_launch(void* const* d_in, const int* in_sizes, int n_in,
                              void* d_out, int out_size, void* d_ws, size_t ws_size,
                              hipStream_t stream)
{
  const float* x    = (const float*)d_in[0];
  const float* bn_w = (const float*)d_in[1];
  const float* bn_b = (const float*)d_in[2];
  const float* wih[4]; const float* whh[4]; const float* bih[4]; const float* bhh[4];
  for (int l = 0; l < 4; ++l) {
    wih[l] = (const float*)d_in[3 + 4 * l];
    whh[l] = (const float*)d_in[4 + 4 * l];
    bih[l] = (const float*)d_in[5 + 4 * l];
    bhh[l] = (const float*)d_in[6 + 4 * l];
  }
  float* out = (float*)d_out;

  const size_t XN  = (size_t)NSTEP * 64;
  const size_t NH1 = (size_t)(NSTEP + 1) * 2048;
  const size_t NH2 = (size_t)(NSTEP + 1) * 1024;
  const size_t NH3 = (size_t)(NSTEP + 1) * 512;
  const size_t NH4 = (size_t)(NSTEP + 1) * 256;
  const size_t BARB = 8192;   // 4 x 512 u32 barrier regions
  const size_t need = BARB + (XN + NH1 + NH2 + NH3 + NH4) * sizeof(float);

  if (ws_size >= need) {
    unsigned* bar = (unsigned*)d_ws;          // 4 x 512 u32 regions (L1..L4)
    float* fb = (float*)((char*)d_ws + BARB);
    float* xn = fb;
    float* H1 = xn + XN;
    float* H2 = H1 + NH1;
    float* H3 = H2 + NH2;
    float* H4 = H3 + NH3;

    hipMemsetAsync(bar, 0, BARB, stream);
    hipMemsetAsync(H1, 0, 2048 * sizeof(float), stream);
    hipMemsetAsync(H2, 0, 1024 * sizeof(float), stream);
    hipMemsetAsync(H3, 0,  512 * sizeof(float), stream);
    hipMemsetAsync(H4, 0,  256 * sizeof(float), stream);

    bn_kernel<<<1024, 256, 0, stream>>>(x, bn_w, bn_b, xn);

    lstm_all<<<480, 512, 0, stream>>>(wih[0], whh[0], bih[0], bhh[0],
                                      wih[1], whh[1], bih[1], bhh[1],
                                      wih[2], whh[2], bih[2], bhh[2],
                                      wih[3], whh[3], bih[3], bhh[3],
                                      xn, H1, H2, H3, H4, out, bar);
    return;
  }

  // -------- fallback: streaming pipeline (proven) --------
  Params p;
  for (int l = 0; l < 4; ++l) { p.w_ih[l] = wih[l]; p.w_hh[l] = whh[l];
                                p.b_ih[l] = bih[l]; p.b_hh[l] = bhh[l]; }
  float* ws = (float*)d_ws;
  float* xn = ws;
  float* st = ws + (size_t)NSTEP * 64;
  p.xn = xn;
  const int Hs[4] = {2048, 1024, 512, 256};
  float* cur = st;
  for (int l = 0; l < 4; ++l) { p.h[l] = cur; cur += 2 * Hs[l]; }
  for (int l = 0; l < 4; ++l) { p.c[l] = cur; cur += Hs[l]; }
  p.out = out;

  const size_t state_bytes = (size_t)(cur - st) * sizeof(float);
  hipMemsetAsync(st, 0, state_bytes, stream);
  bn_kernel<<<1024, 256, 0, stream>>>(x, bn_w, bn_b, xn);
  for (int s = 0; s < NSTEP + 3; ++s) {
    p.s = s;
    step_kernel<<<960, 256, 0, stream>>>(p);
  }
}